// Round 2
// baseline (1170.950 us; speedup 1.0000x reference)
//
#include <hip/hip_runtime.h>
#include <hip/hip_bf16.h>

#define NN 100000
#define EE 500000

typedef __attribute__((ext_vector_type(8))) short short8v;
typedef __attribute__((ext_vector_type(4))) float f32x4;

__device__ __forceinline__ short f2bf(float f) {
  unsigned u = __builtin_bit_cast(unsigned, f);
  u += 0x7fffu + ((u >> 16) & 1u);
  return (short)(u >> 16);
}
__device__ __forceinline__ float bf2f(short s) {
  unsigned u = ((unsigned)(unsigned short)s) << 16;
  return __builtin_bit_cast(float, u);
}

// ---------------- K0: weights -> bf16 fragment-order layouts ----------------
// Btfrag element index: cb*16384 + tn8*2048 + kt*512 + lane*8 + b
//   value = W_cb[k][c], k = kt*32 + (lane>>4)*8 + b, c = tn8*16 + (lane&15)
// Wefrag element index: cg*16384 + tn*4096 + kt*512 + lane*8 + b
//   value = We[k][c],  k = kt*32 + (lane>>4)*8 + b, c = cg*64 + tn*16 + (lane&15)
__global__ __launch_bounds__(256) void k_prep(
    const float* __restrict__ Wq, const float* __restrict__ Wk,
    const float* __restrict__ Wv, const float* __restrict__ Wsk,
    const float* __restrict__ We,
    short* __restrict__ Btfrag, short* __restrict__ Wefrag)
{
  int idx = blockIdx.x * 256 + threadIdx.x;
  if (idx < 65536) {
    int b = idx & 7, lane = (idx >> 3) & 63, kt = (idx >> 9) & 3, tn = (idx >> 11) & 7, cb = idx >> 14;
    int k = kt * 32 + (lane >> 4) * 8 + b;
    int c = tn * 16 + (lane & 15);
    const float* W = cb == 0 ? Wq : cb == 1 ? Wk : cb == 2 ? Wv : Wsk;
    Btfrag[idx] = f2bf(W[k * 128 + c]);
  } else if (idx < 98304) {
    int i2 = idx - 65536;
    int b = i2 & 7, lane = (i2 >> 3) & 63, kt = (i2 >> 9) & 7, tn = (i2 >> 12) & 3, cg = i2 >> 14;
    int k = kt * 32 + (lane >> 4) * 8 + b;
    int c = cg * 64 + tn * 16 + (lane & 15);
    Wefrag[i2] = f2bf(We[k * 128 + c]);
  }
}

// ---------------- K1: x -> bf16 ---------------------------------------------
__global__ __launch_bounds__(256) void k_xcast(const float* __restrict__ x,
                                               unsigned short* __restrict__ xb)
{
  size_t base = ((size_t)blockIdx.x * 256 + threadIdx.x) * 8;
  f32x4 a = *(const f32x4*)(x + base);
  f32x4 b = *(const f32x4*)(x + base + 4);
  short8v w;
  #pragma unroll
  for (int j = 0; j < 4; ++j) { w[j] = f2bf(a[j]); w[4 + j] = f2bf(b[j]); }
  *(short8v*)(xb + base) = w;
}

__global__ __launch_bounds__(256) void k_zero(int* __restrict__ p, int n)
{
  int i = blockIdx.x * 256 + threadIdx.x;
  if (i < n) p[i] = 0;
}

// ---------------- counting sort by dst --------------------------------------
__global__ __launch_bounds__(256) void k_hist(const int* __restrict__ ei, int* __restrict__ cnt)
{
  int e = blockIdx.x * 256 + threadIdx.x;
  if (e < EE) atomicAdd(&cnt[ei[EE + e]], 1);
}

__global__ __launch_bounds__(256) void k_scan_a(const int* __restrict__ cnt,
    int* __restrict__ offtmp, int* __restrict__ bsum)
{
  __shared__ int sc[256];
  int t = threadIdx.x;
  int i = blockIdx.x * 256 + t;
  int v = (i < NN) ? cnt[i] : 0;
  sc[t] = v;
  __syncthreads();
  for (int d = 1; d < 256; d <<= 1) {
    int add = (t >= d) ? sc[t - d] : 0;
    __syncthreads();
    sc[t] += add;
    __syncthreads();
  }
  if (i < NN) offtmp[i] = sc[t] - v;   // exclusive within block
  if (t == 255) bsum[blockIdx.x] = sc[255];
}

__global__ __launch_bounds__(512) void k_scan_b(const int* __restrict__ bsum,
                                                int* __restrict__ bbase)
{
  __shared__ int sc[512];
  int t = threadIdx.x;
  int v = (t < 391) ? bsum[t] : 0;
  sc[t] = v;
  __syncthreads();
  for (int d = 1; d < 512; d <<= 1) {
    int add = (t >= d) ? sc[t - d] : 0;
    __syncthreads();
    sc[t] += add;
    __syncthreads();
  }
  bbase[t] = sc[t] - v;   // exclusive block bases
}

__global__ __launch_bounds__(256) void k_scatter(const int* __restrict__ ei,
    const int* __restrict__ offtmp, const int* __restrict__ bbase,
    int* __restrict__ cur, int* __restrict__ sorted)
{
  int e = blockIdx.x * 256 + threadIdx.x;
  if (e < EE) {
    int d = ei[EE + e];
    int pos = offtmp[d] + bbase[d >> 8] + atomicAdd(&cur[d], 1);
    sorted[pos] = e;
  }
}

// ---------------- K_main: per-64-dst-node block, everything fused -----------
__global__ __launch_bounds__(512) void k_main(
    const unsigned short* __restrict__ xb, const int* __restrict__ ei,
    const float* __restrict__ tt, const float* __restrict__ lu,
    const float* __restrict__ msg,
    const float* __restrict__ timew, const float* __restrict__ timeb,
    const short* __restrict__ Btfrag, const short* __restrict__ Wefrag,
    const float* __restrict__ bq, const float* __restrict__ bk,
    const float* __restrict__ bv, const float* __restrict__ bsk,
    const int* __restrict__ offtmp, const int* __restrict__ bbase,
    const int* __restrict__ sorted,
    float* __restrict__ out)
{
  __shared__ short ATT[64][392];       // [slot][0:128 x_src | 128:256 time | 256:384 msg]
  __shared__ short qlds[64][136];      // q bf16 per owned node
  __shared__ short kvs[2][64][136];    // bf16 (k+bk+e), (v+bv+e) per edge slot
  __shared__ float accum[64][130];     // f32 numerator per owned node
  __shared__ float sden[64][2];        // f32 denominator per owned node x head
  __shared__ int   src_s[64], dslot_s[64], eid_s[64];
  __shared__ float relt_s[64];

  int tid = threadIdx.x;
  int nb0 = blockIdx.x * 64;
  int wid = tid >> 6, lane = tid & 63;
  int eg = wid >> 1, cg = wid & 1;         // wave quadrant: 16 rows x 64 cols
  int lr = lane & 15, lk = (lane >> 4) * 8;
  int rsub = (lane >> 4) * 4;

  // ---- phase 0: stage x[dst tile] (bf16) into ATT cols 0:128; zero accum/sden
  {
    int r = tid >> 3, p = tid & 7;
    int node = nb0 + r;
    short8v a = {0,0,0,0,0,0,0,0}, b = {0,0,0,0,0,0,0,0};
    if (node < NN) {
      const unsigned short* xp = xb + (size_t)node * 128 + p * 16;
      a = *(const short8v*)xp;
      b = *(const short8v*)(xp + 8);
    }
    *(short8v*)&ATT[r][p * 16] = a;
    *(short8v*)&ATT[r][p * 16 + 8] = b;
  }
  {
    float* ac = &accum[0][0];
    for (int i = tid; i < 64 * 130; i += 512) ac[i] = 0.f;
    if (tid < 128) sden[tid >> 1][tid & 1] = 0.f;
  }
  __syncthreads();

  // ---- phase 1: q -> qlds (bf16), skip -> registers (f32, held through loop)
  f32x4 skacc[4];
  {
    f32x4 qacc[4];
    #pragma unroll
    for (int tn = 0; tn < 4; ++tn) {
      qacc[tn] = (f32x4){0.f, 0.f, 0.f, 0.f};
      skacc[tn] = (f32x4){0.f, 0.f, 0.f, 0.f};
    }
    #pragma unroll
    for (int kt = 0; kt < 4; ++kt) {
      short8v a = *(const short8v*)&ATT[eg * 16 + lr][kt * 32 + lk];
      #pragma unroll
      for (int tn = 0; tn < 4; ++tn) {
        short8v bqf = *(const short8v*)(Btfrag + (size_t)(((0 * 8 + cg * 4 + tn) * 4 + kt) * 64 + lane) * 8);
        short8v bsf = *(const short8v*)(Btfrag + (size_t)(((3 * 8 + cg * 4 + tn) * 4 + kt) * 64 + lane) * 8);
        qacc[tn] = __builtin_amdgcn_mfma_f32_16x16x32_bf16(a, bqf, qacc[tn], 0, 0, 0);
        skacc[tn] = __builtin_amdgcn_mfma_f32_16x16x32_bf16(a, bsf, skacc[tn], 0, 0, 0);
      }
    }
    #pragma unroll
    for (int tn = 0; tn < 4; ++tn) {
      int c = cg * 64 + tn * 16 + lr;
      float bqa = bq[c];
      #pragma unroll
      for (int rg = 0; rg < 4; ++rg)
        qlds[eg * 16 + rsub + rg][c] = f2bf(qacc[tn][rg] + bqa);
    }
  }
  __syncthreads();

  int beg = offtmp[nb0] + bbase[nb0 >> 8];
  int end = (nb0 + 64 < NN) ? (offtmp[nb0 + 64] + bbase[(nb0 + 64) >> 8]) : EE;

  for (int t0 = beg; t0 < end; t0 += 64) {
    __syncthreads();   // protect meta arrays from previous tile's readers
    if (tid < 64) {
      int i = t0 + tid;
      int ds = -1, sv = 0, eid = 0; float rt = 0.f;
      if (i < end) {
        eid = sorted[i];
        sv = ei[eid];
        ds = ei[EE + eid] - nb0;       // in [0,64) by construction of the sort
        rt = tt[eid] - lu[sv];
      }
      dslot_s[tid] = ds; src_s[tid] = sv; eid_s[tid] = eid; relt_s[tid] = rt;
    }
    __syncthreads();

    // ---- build ATT: x[src] | cos-time | msg (8 threads x 16 cols each part)
    {
      int el = tid >> 3, p = tid & 7;
      bool val = dslot_s[el] >= 0;
      int sv = src_s[el], eid = eid_s[el];
      float rt = relt_s[el];
      short8v xa = {0,0,0,0,0,0,0,0}, xb2 = {0,0,0,0,0,0,0,0};
      if (val) {
        const unsigned short* xp = xb + (size_t)sv * 128 + p * 16;
        xa = *(const short8v*)xp;
        xb2 = *(const short8v*)(xp + 8);
      }
      *(short8v*)&ATT[el][p * 16] = xa;
      *(short8v*)&ATT[el][p * 16 + 8] = xb2;

      short8v ta, tb2;
      #pragma unroll
      for (int j = 0; j < 8; ++j) {
        int c = p * 16 + j;
        ta[j] = f2bf(val ? __cosf(fmaf(rt, timew[c], timeb[c])) : 0.f);
      }
      #pragma unroll
      for (int j = 0; j < 8; ++j) {
        int c = p * 16 + 8 + j;
        tb2[j] = f2bf(val ? __cosf(fmaf(rt, timew[c], timeb[c])) : 0.f);
      }
      *(short8v*)&ATT[el][128 + p * 16] = ta;
      *(short8v*)&ATT[el][128 + p * 16 + 8] = tb2;

      short8v ma = {0,0,0,0,0,0,0,0}, mb2 = {0,0,0,0,0,0,0,0};
      if (val) {
        const float* mp = msg + (size_t)eid * 128 + p * 16;
        f32x4 m0 = *(const f32x4*)(mp);
        f32x4 m1 = *(const f32x4*)(mp + 4);
        f32x4 m2 = *(const f32x4*)(mp + 8);
        f32x4 m3 = *(const f32x4*)(mp + 12);
        #pragma unroll
        for (int j = 0; j < 4; ++j) {
          ma[j] = f2bf(m0[j]); ma[4 + j] = f2bf(m1[j]);
          mb2[j] = f2bf(m2[j]); mb2[4 + j] = f2bf(m3[j]);
        }
      }
      *(short8v*)&ATT[el][256 + p * 16] = ma;
      *(short8v*)&ATT[el][256 + p * 16 + 8] = mb2;
    }
    __syncthreads();

    // ---- MFMA: e (K=256 over time|msg), k,v (K=128 over x[src]) -> kvs bf16
    {
      f32x4 ae[4], ak[4], av[4];
      #pragma unroll
      for (int tn = 0; tn < 4; ++tn) {
        ae[tn] = (f32x4){0.f, 0.f, 0.f, 0.f};
        ak[tn] = (f32x4){0.f, 0.f, 0.f, 0.f};
        av[tn] = (f32x4){0.f, 0.f, 0.f, 0.f};
      }
      #pragma unroll
      for (int kt = 0; kt < 8; ++kt) {
        short8v a = *(const short8v*)&ATT[eg * 16 + lr][128 + kt * 32 + lk];
        #pragma unroll
        for (int tn = 0; tn < 4; ++tn) {
          short8v bf = *(const short8v*)(Wefrag + (size_t)(((cg * 4 + tn) * 8 + kt) * 64 + lane) * 8);
          ae[tn] = __builtin_amdgcn_mfma_f32_16x16x32_bf16(a, bf, ae[tn], 0, 0, 0);
        }
      }
      #pragma unroll
      for (int kt = 0; kt < 4; ++kt) {
        short8v a = *(const short8v*)&ATT[eg * 16 + lr][kt * 32 + lk];
        #pragma unroll
        for (int tn = 0; tn < 4; ++tn) {
          short8v bkf = *(const short8v*)(Btfrag + (size_t)(((1 * 8 + cg * 4 + tn) * 4 + kt) * 64 + lane) * 8);
          short8v bvf = *(const short8v*)(Btfrag + (size_t)(((2 * 8 + cg * 4 + tn) * 4 + kt) * 64 + lane) * 8);
          ak[tn] = __builtin_amdgcn_mfma_f32_16x16x32_bf16(a, bkf, ak[tn], 0, 0, 0);
          av[tn] = __builtin_amdgcn_mfma_f32_16x16x32_bf16(a, bvf, av[tn], 0, 0, 0);
        }
      }
      #pragma unroll
      for (int tn = 0; tn < 4; ++tn) {
        int c = cg * 64 + tn * 16 + lr;
        float bka = bk[c], bva = bv[c];
        #pragma unroll
        for (int rg = 0; rg < 4; ++rg) {
          int row = eg * 16 + rsub + rg;
          kvs[0][row][c] = f2bf(ak[tn][rg] + bka + ae[tn][rg]);
          kvs[1][row][c] = f2bf(av[tn][rg] + bva + ae[tn][rg]);
        }
      }
    }
    __syncthreads();

    // ---- dot + exp + LDS accumulation (8 threads per edge, 16 ch each)
    {
      int el = tid >> 3, p = tid & 7;
      int ds = dslot_s[el];
      int dsx = ds < 0 ? 0 : ds;
      int c0 = p * 16;
      short8v qa = *(const short8v*)&qlds[dsx][c0];
      short8v qb = *(const short8v*)&qlds[dsx][c0 + 8];
      short8v ka = *(const short8v*)&kvs[0][el][c0];
      short8v kb = *(const short8v*)&kvs[0][el][c0 + 8];
      float dot = 0.f;
      #pragma unroll
      for (int j = 0; j < 8; ++j)
        dot += bf2f(qa[j]) * bf2f(ka[j]) + bf2f(qb[j]) * bf2f(kb[j]);
      dot += __shfl_xor(dot, 1);
      dot += __shfl_xor(dot, 2);   // 4-lane head group now holds the full dot
      float pex = __expf(dot * 0.125f);   // deferred softmax: exp arg bounded ~|20|
      if (ds >= 0) {
        if ((p & 3) == 0) atomicAdd(&sden[ds][p >> 2], pex);
        short8v va = *(const short8v*)&kvs[1][el][c0];
        short8v vb = *(const short8v*)&kvs[1][el][c0 + 8];
        #pragma unroll
        for (int j = 0; j < 8; ++j) {
          atomicAdd(&accum[ds][c0 + j], pex * bf2f(va[j]));
          atomicAdd(&accum[ds][c0 + 8 + j], pex * bf2f(vb[j]));
        }
      }
    }
  }
  __syncthreads();

  // ---- final: out = skip + bsk + accum / (sden + eps), one write per element
  #pragma unroll
  for (int tn = 0; tn < 4; ++tn) {
    int c = cg * 64 + tn * 16 + lr;
    float bska = bsk[c];
    #pragma unroll
    for (int rg = 0; rg < 4; ++rg) {
      int row = eg * 16 + rsub + rg;
      int node = nb0 + row;
      if (node < NN) {
        float den = sden[row][cg] + 1e-16f;
        out[(size_t)node * 128 + c] = skacc[tn][rg] + bska + accum[row][c] / den;
      }
    }
  }
}

extern "C" void kernel_launch(void* const* d_in, const int* in_sizes, int n_in,
                              void* d_out, int out_size, void* d_ws, size_t ws_size,
                              hipStream_t stream) {
  const float* x    = (const float*)d_in[0];
  const float* lu   = (const float*)d_in[1];
  const float* tt   = (const float*)d_in[2];
  const float* msg  = (const float*)d_in[3];
  const int*   ei   = (const int*)d_in[4];
  const float* timew = (const float*)d_in[5];
  const float* timeb = (const float*)d_in[6];
  const float* Wq   = (const float*)d_in[7];
  const float* bq   = (const float*)d_in[8];
  const float* Wk   = (const float*)d_in[9];
  const float* bk   = (const float*)d_in[10];
  const float* Wv   = (const float*)d_in[11];
  const float* bv   = (const float*)d_in[12];
  const float* We   = (const float*)d_in[13];
  const float* Wsk  = (const float*)d_in[14];
  const float* bsk  = (const float*)d_in[15];
  float* out = (float*)d_out;

  char* wsp = (char*)d_ws;
  // ws layout (bytes, 16B-aligned), total 29.0 MB:
  //   [0,          25,600,000)  xb      (N*128 bf16)
  //   [25,600,000, 25,731,072)  Btfrag  (65,536 bf16)
  //   [25,731,072, 25,796,608)  Wefrag  (32,768 bf16)
  //   [25,796,608, 26,196,608)  cnt     (N i32)
  //   [26,196,608, 26,596,608)  cur     (N i32)   (contiguous with cnt for one zero pass)
  //   [26,596,608, 26,996,992)  offtmp  (100,096 i32)
  //   [26,996,992, 26,999,040)  bsum    (512 i32)
  //   [26,999,040, 27,001,088)  bbase   (512 i32)
  //   [27,001,088, 29,001,088)  sorted  (E i32)
  unsigned short* xbw = (unsigned short*)wsp;
  short* Btfrag = (short*)(wsp + 25600000);
  short* Wefrag = (short*)(wsp + 25731072);
  int* cnt      = (int*)(wsp + 25796608);
  int* cur      = (int*)(wsp + 26196608);
  int* offtmp   = (int*)(wsp + 26596608);
  int* bsum     = (int*)(wsp + 26996992);
  int* bbase    = (int*)(wsp + 26999040);
  int* sorted   = (int*)(wsp + 27001088);

  k_zero<<<782, 256, 0, stream>>>(cnt, 200000);           // cnt + cur
  k_prep<<<384, 256, 0, stream>>>(Wq, Wk, Wv, Wsk, We, Btfrag, Wefrag);
  k_xcast<<<6250, 256, 0, stream>>>(x, xbw);
  k_hist<<<1954, 256, 0, stream>>>(ei, cnt);
  k_scan_a<<<391, 256, 0, stream>>>(cnt, offtmp, bsum);
  k_scan_b<<<1, 512, 0, stream>>>(bsum, bbase);
  k_scatter<<<1954, 256, 0, stream>>>(ei, offtmp, bbase, cur, sorted);
  k_main<<<1563, 512, 0, stream>>>(xbw, ei, tt, lu, msg, timew, timeb,
                                   Btfrag, Wefrag, bq, bk, bv, bsk,
                                   offtmp, bbase, sorted, out);
}

// Round 3
// 666.789 us; speedup vs baseline: 1.7561x; 1.7561x over previous
//
#include <hip/hip_runtime.h>
#include <hip/hip_bf16.h>

#define NN 100000
#define EE 500000

typedef __attribute__((ext_vector_type(8))) short short8v;
typedef __attribute__((ext_vector_type(4))) float f32x4;

__device__ __forceinline__ short f2bf(float f) {
  unsigned u = __builtin_bit_cast(unsigned, f);
  u += 0x7fffu + ((u >> 16) & 1u);
  return (short)(u >> 16);
}
__device__ __forceinline__ float bf2f(short s) {
  unsigned u = ((unsigned)(unsigned short)s) << 16;
  return __builtin_bit_cast(float, u);
}

// ---------------- K0: weights -> bf16 fragment-order layouts ----------------
// Btfrag element index: ((cb*8 + strip)*4 + kt)*512 + lane*8 + b
//   value = W_cb[k][c], k = kt*32 + (lane>>4)*8 + b, c = strip*16 + (lane&15)
// Wefrag element index: ((strip*8 + kt))*512 + lane*8 + b
//   value = We[k][c],  k = kt*32 + (lane>>4)*8 + b, c = strip*16 + (lane&15)
__global__ __launch_bounds__(256) void k_prep(
    const float* __restrict__ Wq, const float* __restrict__ Wk,
    const float* __restrict__ Wv, const float* __restrict__ Wsk,
    const float* __restrict__ We,
    short* __restrict__ Btfrag, short* __restrict__ Wefrag)
{
  int idx = blockIdx.x * 256 + threadIdx.x;
  if (idx < 65536) {
    int b = idx & 7, lane = (idx >> 3) & 63, kt = (idx >> 9) & 3, tn = (idx >> 11) & 7, cb = idx >> 14;
    int k = kt * 32 + (lane >> 4) * 8 + b;
    int c = tn * 16 + (lane & 15);
    const float* W = cb == 0 ? Wq : cb == 1 ? Wk : cb == 2 ? Wv : Wsk;
    Btfrag[idx] = f2bf(W[k * 128 + c]);
  } else if (idx < 98304) {
    int i2 = idx - 65536;
    int b = i2 & 7, lane = (i2 >> 3) & 63, kt = (i2 >> 9) & 7, strip = i2 >> 12;
    int k = kt * 32 + (lane >> 4) * 8 + b;
    int c = strip * 16 + (lane & 15);
    Wefrag[i2] = f2bf(We[k * 128 + c]);
  }
}

// ---------------- K1: x -> bf16 ---------------------------------------------
__global__ __launch_bounds__(256) void k_xcast(const float* __restrict__ x,
                                               unsigned short* __restrict__ xb)
{
  size_t base = ((size_t)blockIdx.x * 256 + threadIdx.x) * 8;
  f32x4 a = *(const f32x4*)(x + base);
  f32x4 b = *(const f32x4*)(x + base + 4);
  short8v w;
  #pragma unroll
  for (int j = 0; j < 4; ++j) { w[j] = f2bf(a[j]); w[4 + j] = f2bf(b[j]); }
  *(short8v*)(xb + base) = w;
}

__global__ __launch_bounds__(256) void k_zero(int* __restrict__ p, int n)
{
  int i = blockIdx.x * 256 + threadIdx.x;
  if (i < n) p[i] = 0;
}

// ---------------- counting sort by dst --------------------------------------
__global__ __launch_bounds__(256) void k_hist(const int* __restrict__ ei, int* __restrict__ cnt)
{
  int e = blockIdx.x * 256 + threadIdx.x;
  if (e < EE) atomicAdd(&cnt[ei[EE + e]], 1);
}

__global__ __launch_bounds__(256) void k_scan_a(const int* __restrict__ cnt,
    int* __restrict__ offtmp, int* __restrict__ bsum)
{
  __shared__ int sc[256];
  int t = threadIdx.x;
  int i = blockIdx.x * 256 + t;
  int v = (i < NN) ? cnt[i] : 0;
  sc[t] = v;
  __syncthreads();
  for (int d = 1; d < 256; d <<= 1) {
    int add = (t >= d) ? sc[t - d] : 0;
    __syncthreads();
    sc[t] += add;
    __syncthreads();
  }
  if (i < NN) offtmp[i] = sc[t] - v;   // exclusive within block
  if (t == 255) bsum[blockIdx.x] = sc[255];
}

__global__ __launch_bounds__(512) void k_scan_b(const int* __restrict__ bsum,
                                                int* __restrict__ bbase)
{
  __shared__ int sc[512];
  int t = threadIdx.x;
  int v = (t < 391) ? bsum[t] : 0;
  sc[t] = v;
  __syncthreads();
  for (int d = 1; d < 512; d <<= 1) {
    int add = (t >= d) ? sc[t - d] : 0;
    __syncthreads();
    sc[t] += add;
    __syncthreads();
  }
  bbase[t] = sc[t] - v;   // exclusive block bases
}

__global__ __launch_bounds__(256) void k_scatter(const int* __restrict__ ei,
    const int* __restrict__ offtmp, const int* __restrict__ bbase,
    int* __restrict__ cur, int* __restrict__ sorted)
{
  int e = blockIdx.x * 256 + threadIdx.x;
  if (e < EE) {
    int d = ei[EE + e];
    int pos = offtmp[d] + bbase[d >> 8] + atomicAdd(&cur[d], 1);
    sorted[pos] = e;
  }
}

// ---------------- K_emeta: flatten the per-edge dependency chain ------------
__global__ __launch_bounds__(256) void k_emeta(const int* __restrict__ ei,
    const float* __restrict__ tt, const float* __restrict__ lu,
    const int* __restrict__ sorted,
    int* __restrict__ src_sorted, int* __restrict__ dst_sorted,
    float* __restrict__ relt_sorted)
{
  int i = blockIdx.x * 256 + threadIdx.x;
  if (i < EE) {
    int eid = sorted[i];
    int sv = ei[eid];
    src_sorted[i] = sv;
    dst_sorted[i] = ei[EE + eid];
    relt_sorted[i] = tt[eid] - lu[sv];
  }
}

// ---------------- K_main: per-64-dst-node block, fused, weights-in-regs -----
__global__ __launch_bounds__(512) void k_main(
    const unsigned short* __restrict__ xb,
    const float* __restrict__ msg,
    const float* __restrict__ timew, const float* __restrict__ timeb,
    const short* __restrict__ Btfrag, const short* __restrict__ Wefrag,
    const float* __restrict__ bq, const float* __restrict__ bk,
    const float* __restrict__ bv, const float* __restrict__ bsk,
    const int* __restrict__ offtmp, const int* __restrict__ bbase,
    const int* __restrict__ sorted, const int* __restrict__ src_sorted,
    const int* __restrict__ dst_sorted, const float* __restrict__ relt_sorted,
    float* __restrict__ out)
{
  __shared__ short ATT[64][392];       // [slot][0:128 x_src | 128:256 time | 256:384 msg]
  __shared__ short qlds[64][136];      // q bf16 per owned node
  __shared__ short kvs[2][64][136];    // bf16 (k+bk+e), (v+bv+e) per edge slot
  __shared__ float accum[64][130];     // f32 numerator per owned node
  __shared__ float sden[64][2];        // f32 denominator per owned node x head

  const int tid = threadIdx.x;
  const int nb0 = blockIdx.x * 64;
  const int wid = tid >> 6, lane = tid & 63;
  const int lr = lane & 15, lk = (lane >> 4) * 8, rsub = (lane >> 4) * 4;
  const int el = tid >> 3, p = tid & 7;
  const int cme = wid * 16 + lr;        // this wave's output column strip

  // ---- zero LDS accumulators
  {
    float* ac = &accum[0][0];
    for (int i = tid; i < 64 * 130; i += 512) ac[i] = 0.f;
    if (tid < 128) sden[tid >> 1][tid & 1] = 0.f;
  }

  // ---- per-wave weight fragments -> registers (once per block, L2-hot)
  short8v wef[8], wkf[4], wvf[4];
  #pragma unroll
  for (int kt = 0; kt < 8; ++kt)
    wef[kt] = *(const short8v*)(Wefrag + (size_t)((wid * 8 + kt) * 64 + lane) * 8);
  #pragma unroll
  for (int kt = 0; kt < 4; ++kt) {
    wkf[kt] = *(const short8v*)(Btfrag + (size_t)(((8 + wid) * 4 + kt) * 64 + lane) * 8);
    wvf[kt] = *(const short8v*)(Btfrag + (size_t)(((16 + wid) * 4 + kt) * 64 + lane) * 8);
  }
  const float bqc = bq[cme], bkc = bk[cme], bvc = bv[cme], bskc = bsk[cme];

  // ---- stage x[dst tile] (bf16) into ATT cols 0:128
  {
    int node = nb0 + el;
    short8v a = {0,0,0,0,0,0,0,0}, b = {0,0,0,0,0,0,0,0};
    if (node < NN) {
      const unsigned short* xp = xb + (size_t)node * 128 + p * 16;
      a = *(const short8v*)xp;
      b = *(const short8v*)(xp + 8);
    }
    *(short8v*)&ATT[el][p * 16] = a;
    *(short8v*)&ATT[el][p * 16 + 8] = b;
  }
  __syncthreads();

  // ---- prologue: q -> qlds (bf16), skip -> registers (f32)
  f32x4 skacc[4];
  {
    f32x4 qacc[4];
    #pragma unroll
    for (int eg = 0; eg < 4; ++eg) {
      qacc[eg] = (f32x4){0.f, 0.f, 0.f, 0.f};
      skacc[eg] = (f32x4){0.f, 0.f, 0.f, 0.f};
    }
    #pragma unroll
    for (int kt = 0; kt < 4; ++kt) {
      short8v bqf = *(const short8v*)(Btfrag + (size_t)(((0 + wid) * 4 + kt) * 64 + lane) * 8);
      short8v bsf = *(const short8v*)(Btfrag + (size_t)(((24 + wid) * 4 + kt) * 64 + lane) * 8);
      #pragma unroll
      for (int eg = 0; eg < 4; ++eg) {
        short8v a = *(const short8v*)&ATT[eg * 16 + lr][kt * 32 + lk];
        qacc[eg] = __builtin_amdgcn_mfma_f32_16x16x32_bf16(a, bqf, qacc[eg], 0, 0, 0);
        skacc[eg] = __builtin_amdgcn_mfma_f32_16x16x32_bf16(a, bsf, skacc[eg], 0, 0, 0);
      }
    }
    #pragma unroll
    for (int eg = 0; eg < 4; ++eg)
      #pragma unroll
      for (int rg = 0; rg < 4; ++rg)
        qlds[eg * 16 + rsub + rg][cme] = f2bf(qacc[eg][rg] + bqc);
  }

  const int beg = offtmp[nb0] + bbase[nb0 >> 8];
  const int end = (nb0 + 64 < NN) ? (offtmp[nb0 + 64] + bbase[(nb0 + 64) >> 8]) : EE;

  // ---- prefetch tile 0 into registers
  int pdst = 0; float prelt = 0.f;
  short8v px0 = {0,0,0,0,0,0,0,0}, px1 = {0,0,0,0,0,0,0,0};
  f32x4 pm0 = {0.f,0.f,0.f,0.f}, pm1 = pm0, pm2 = pm0, pm3 = pm0;
  {
    int i = beg + el;
    if (i < end) {
      int eid = sorted[i];
      int sv = src_sorted[i];
      pdst = dst_sorted[i];
      prelt = relt_sorted[i];
      const unsigned short* xp = xb + (size_t)sv * 128 + p * 16;
      px0 = *(const short8v*)xp;
      px1 = *(const short8v*)(xp + 8);
      const float* mp = msg + (size_t)eid * 128 + p * 16;
      pm0 = *(const f32x4*)mp;       pm1 = *(const f32x4*)(mp + 4);
      pm2 = *(const f32x4*)(mp + 8); pm3 = *(const f32x4*)(mp + 12);
    }
  }
  __syncthreads();   // qlds visible; ATT free for per-tile reuse

  for (int t0 = beg; t0 < end; t0 += 64) {
    // ---- S0: commit prefetched tile to ATT
    const int cdst = pdst;
    const bool cval = (t0 + el) < end;
    *(short8v*)&ATT[el][p * 16] = px0;
    *(short8v*)&ATT[el][p * 16 + 8] = px1;
    {
      short8v ta, tb;
      #pragma unroll
      for (int j = 0; j < 8; ++j) {
        int c = p * 16 + j;
        ta[j] = f2bf(__cosf(fmaf(prelt, timew[c], timeb[c])));
      }
      #pragma unroll
      for (int j = 0; j < 8; ++j) {
        int c = p * 16 + 8 + j;
        tb[j] = f2bf(__cosf(fmaf(prelt, timew[c], timeb[c])));
      }
      *(short8v*)&ATT[el][128 + p * 16] = ta;
      *(short8v*)&ATT[el][128 + p * 16 + 8] = tb;
    }
    {
      short8v ma, mb;
      #pragma unroll
      for (int j = 0; j < 4; ++j) {
        ma[j] = f2bf(pm0[j]); ma[4 + j] = f2bf(pm1[j]);
        mb[j] = f2bf(pm2[j]); mb[4 + j] = f2bf(pm3[j]);
      }
      *(short8v*)&ATT[el][256 + p * 16] = ma;
      *(short8v*)&ATT[el][256 + p * 16 + 8] = mb;
    }
    __syncthreads();

    // ---- S1: issue next-tile prefetch, then MFMA e/k/v -> kvs
    {
      int i = t0 + 64 + el;
      if (i < end) {
        int eid = sorted[i];
        int sv = src_sorted[i];
        pdst = dst_sorted[i];
        prelt = relt_sorted[i];
        const unsigned short* xp = xb + (size_t)sv * 128 + p * 16;
        px0 = *(const short8v*)xp;
        px1 = *(const short8v*)(xp + 8);
        const float* mp = msg + (size_t)eid * 128 + p * 16;
        pm0 = *(const f32x4*)mp;       pm1 = *(const f32x4*)(mp + 4);
        pm2 = *(const f32x4*)(mp + 8); pm3 = *(const f32x4*)(mp + 12);
      }
    }
    {
      f32x4 ae[4], ak[4], av[4];
      #pragma unroll
      for (int eg = 0; eg < 4; ++eg) {
        ae[eg] = (f32x4){0.f, 0.f, 0.f, 0.f};
        ak[eg] = (f32x4){0.f, 0.f, 0.f, 0.f};
        av[eg] = (f32x4){0.f, 0.f, 0.f, 0.f};
      }
      #pragma unroll
      for (int kt = 0; kt < 8; ++kt)
        #pragma unroll
        for (int eg = 0; eg < 4; ++eg) {
          short8v a = *(const short8v*)&ATT[eg * 16 + lr][128 + kt * 32 + lk];
          ae[eg] = __builtin_amdgcn_mfma_f32_16x16x32_bf16(a, wef[kt], ae[eg], 0, 0, 0);
        }
      #pragma unroll
      for (int kt = 0; kt < 4; ++kt)
        #pragma unroll
        for (int eg = 0; eg < 4; ++eg) {
          short8v a = *(const short8v*)&ATT[eg * 16 + lr][kt * 32 + lk];
          ak[eg] = __builtin_amdgcn_mfma_f32_16x16x32_bf16(a, wkf[kt], ak[eg], 0, 0, 0);
          av[eg] = __builtin_amdgcn_mfma_f32_16x16x32_bf16(a, wvf[kt], av[eg], 0, 0, 0);
        }
      #pragma unroll
      for (int eg = 0; eg < 4; ++eg)
        #pragma unroll
        for (int rg = 0; rg < 4; ++rg) {
          int row = eg * 16 + rsub + rg;
          kvs[0][row][cme] = f2bf(ak[eg][rg] + bkc + ae[eg][rg]);
          kvs[1][row][cme] = f2bf(av[eg][rg] + bvc + ae[eg][rg]);
        }
    }
    __syncthreads();

    // ---- S2: dot + exp + LDS accumulation (8 threads/edge, 16 ch each)
    {
      int ds = cval ? (cdst - nb0) : -1;
      int dsx = ds < 0 ? 0 : ds;
      int c0 = p * 16;
      short8v qa = *(const short8v*)&qlds[dsx][c0];
      short8v qb = *(const short8v*)&qlds[dsx][c0 + 8];
      short8v ka = *(const short8v*)&kvs[0][el][c0];
      short8v kb = *(const short8v*)&kvs[0][el][c0 + 8];
      float dot = 0.f;
      #pragma unroll
      for (int j = 0; j < 8; ++j)
        dot += bf2f(qa[j]) * bf2f(ka[j]) + bf2f(qb[j]) * bf2f(kb[j]);
      dot += __shfl_xor(dot, 1);
      dot += __shfl_xor(dot, 2);   // 4-lane head group holds the full dot
      float pex = __expf(dot * 0.125f);
      if (ds >= 0) {
        if ((p & 3) == 0) atomicAdd(&sden[ds][p >> 2], pex);
        short8v va = *(const short8v*)&kvs[1][el][c0];
        short8v vb = *(const short8v*)&kvs[1][el][c0 + 8];
        #pragma unroll
        for (int j = 0; j < 8; ++j) {
          atomicAdd(&accum[ds][c0 + j], pex * bf2f(va[j]));
          atomicAdd(&accum[ds][c0 + 8 + j], pex * bf2f(vb[j]));
        }
      }
    }
    __syncthreads();
  }

  // ---- epilogue: out = skip + bsk + accum / (sden + eps)
  const int hme = wid >> 2;
  #pragma unroll
  for (int eg = 0; eg < 4; ++eg)
    #pragma unroll
    for (int rg = 0; rg < 4; ++rg) {
      int row = eg * 16 + rsub + rg;
      int node = nb0 + row;
      if (node < NN) {
        float den = sden[row][hme] + 1e-16f;
        out[(size_t)node * 128 + cme] = skacc[eg][rg] + bskc + accum[row][cme] / den;
      }
    }
}

extern "C" void kernel_launch(void* const* d_in, const int* in_sizes, int n_in,
                              void* d_out, int out_size, void* d_ws, size_t ws_size,
                              hipStream_t stream) {
  const float* x    = (const float*)d_in[0];
  const float* lu   = (const float*)d_in[1];
  const float* tt   = (const float*)d_in[2];
  const float* msg  = (const float*)d_in[3];
  const int*   ei   = (const int*)d_in[4];
  const float* timew = (const float*)d_in[5];
  const float* timeb = (const float*)d_in[6];
  const float* Wq   = (const float*)d_in[7];
  const float* bq   = (const float*)d_in[8];
  const float* Wk   = (const float*)d_in[9];
  const float* bk   = (const float*)d_in[10];
  const float* Wv   = (const float*)d_in[11];
  const float* bv   = (const float*)d_in[12];
  const float* We   = (const float*)d_in[13];
  const float* Wsk  = (const float*)d_in[14];
  const float* bsk  = (const float*)d_in[15];
  float* out = (float*)d_out;

  char* wsp = (char*)d_ws;
  // ws layout (bytes, 16B-aligned), total 35.0 MB:
  //   [0,          25,600,000)  xb          (N*128 bf16)
  //   [25,600,000, 25,731,072)  Btfrag      (65,536 bf16)
  //   [25,731,072, 25,796,608)  Wefrag      (32,768 bf16)
  //   [25,796,608, 26,196,608)  cnt         (N i32)
  //   [26,196,608, 26,596,608)  cur         (N i32)
  //   [26,596,608, 26,996,992)  offtmp      (100,096 i32)
  //   [26,996,992, 26,999,040)  bsum        (512 i32)
  //   [26,999,040, 27,001,088)  bbase       (512 i32)
  //   [27,001,088, 29,001,088)  sorted      (E i32)
  //   [29,001,088, 31,001,088)  src_sorted  (E i32)
  //   [31,001,088, 33,001,088)  dst_sorted  (E i32)
  //   [33,001,088, 35,001,088)  relt_sorted (E f32)
  unsigned short* xbw = (unsigned short*)wsp;
  short* Btfrag = (short*)(wsp + 25600000);
  short* Wefrag = (short*)(wsp + 25731072);
  int* cnt      = (int*)(wsp + 25796608);
  int* cur      = (int*)(wsp + 26196608);
  int* offtmp   = (int*)(wsp + 26596608);
  int* bsum     = (int*)(wsp + 26996992);
  int* bbase    = (int*)(wsp + 26999040);
  int* sorted   = (int*)(wsp + 27001088);
  int* srcs     = (int*)(wsp + 29001088);
  int* dsts     = (int*)(wsp + 31001088);
  float* relts  = (float*)(wsp + 33001088);

  k_zero<<<782, 256, 0, stream>>>(cnt, 200000);           // cnt + cur
  k_prep<<<384, 256, 0, stream>>>(Wq, Wk, Wv, Wsk, We, Btfrag, Wefrag);
  k_xcast<<<6250, 256, 0, stream>>>(x, xbw);
  k_hist<<<1954, 256, 0, stream>>>(ei, cnt);
  k_scan_a<<<391, 256, 0, stream>>>(cnt, offtmp, bsum);
  k_scan_b<<<1, 512, 0, stream>>>(bsum, bbase);
  k_scatter<<<1954, 256, 0, stream>>>(ei, offtmp, bbase, cur, sorted);
  k_emeta<<<1954, 256, 0, stream>>>(ei, tt, lu, sorted, srcs, dsts, relts);
  k_main<<<1563, 512, 0, stream>>>(xbw, msg, timew, timeb,
                                   Btfrag, Wefrag, bq, bk, bv, bsk,
                                   offtmp, bbase, sorted, srcs, dsts, relts, out);
}